// Round 1
// baseline (380.681 us; speedup 1.0000x reference)
//
#include <hip/hip_runtime.h>
#include <hip/hip_fp16.h>

#define N_NODES 100000
#define IN_DIM 128
#define HID 64
#define NUM_GRAPHS 2048
#define CNE_MAX (1600000 + 7 * N_NODES)   // padded-to-8 CSR upper bound
#define BROWS 128                          // rows per bucket
#define NBUCK ((N_NODES + BROWS - 1) / BROWS)   // 782
#define NCHUNK 256                         // edge chunks (one block each)
#define TOTP (NBUCK * NCHUNK)              // 200192 partial counters
#define CAP 4096                           // LDS staging entries per bucket

typedef _Float16 h8 __attribute__((ext_vector_type(8)));
typedef float f4 __attribute__((ext_vector_type(4)));

// ---------------- build phase (NO per-edge global atomics anywhere) ----------------

// also zeroes the pad rows (row N) of both tmp ping-pong buffers (replaces a memset dispatch)
__global__ __launch_bounds__(256) void hist_partial(const int* __restrict__ dst,
                                                    int* __restrict__ partial,
                                                    int E, int chunk,
                                                    unsigned* __restrict__ padA,
                                                    unsigned* __restrict__ padB) {
    __shared__ int lh[NBUCK];
    int t = threadIdx.x, c = blockIdx.x;
    if (c == 0) {
        if (t < 32) padA[t] = 0;
        else if (t < 64) padB[t - 32] = 0;
    }
    for (int b = t; b < NBUCK; b += 256) lh[b] = 0;
    __syncthreads();
    int lo = c * chunk, hi = min(lo + chunk, E);
    for (int i = lo + t; i < hi; i += 256) atomicAdd(&lh[dst[i] >> 7], 1);
    __syncthreads();
    for (int b = t; b < NBUCK; b += 256) partial[b * NCHUNK + c] = lh[b];
}

// phase 1: per-block (1024 elems) inclusive scan + block sums; pad8 applied when flagged
__global__ void scan1(const int* __restrict__ counts, int* __restrict__ out1,
                      int* __restrict__ bsum, int n, int pad8) {
    __shared__ int s[256];
    int t = threadIdx.x;
    int base = blockIdx.x * 1024 + t * 4;
    int v[4];
#pragma unroll
    for (int i = 0; i < 4; i++) {
        int c = (base + i < n) ? counts[base + i] : 0;
        v[i] = pad8 ? ((c + 7) & ~7) : c;
    }
    int tsum = v[0] + v[1] + v[2] + v[3];
    s[t] = tsum;
    __syncthreads();
    for (int off = 1; off < 256; off <<= 1) {
        int tv = (t >= off) ? s[t - off] : 0;
        __syncthreads();
        s[t] += tv;
        __syncthreads();
    }
    int excl = s[t] - tsum;
    if (t == 255) bsum[blockIdx.x] = s[255];
    int run = excl;
#pragma unroll
    for (int i = 0; i < 4; i++) {
        run += v[i];
        if (base + i < n) out1[base + i] = run;
    }
}

// scan of block sums (nb <= 256) done redundantly per block in LDS (removes scan2 dispatch)
__device__ __forceinline__ int inline_bscan(const int* __restrict__ bsum, int nb, int* s) {
    int t = threadIdx.x;
    int v = (t < nb) ? bsum[t] : 0;
    s[t] = v;
    __syncthreads();
    for (int off = 1; off < 256; off <<= 1) {
        int tv = (t >= off) ? s[t - off] : 0;
        __syncthreads();
        s[t] += tv;
        __syncthreads();
    }
    int excl = s[t] - v;
    __syncthreads();
    s[t] = excl;
    __syncthreads();
    return excl;
}

__global__ __launch_bounds__(256) void scan3(int* __restrict__ row_ptr,
                                             const int* __restrict__ bsum, int nb, int n) {
    __shared__ int s[256];
    inline_bscan(bsum, nb, s);
    int i = blockIdx.x * blockDim.x + threadIdx.x;
    if (i == 0) row_ptr[0] = 0;
    if (i < n) row_ptr[i + 1] += s[i >> 10];
}

__global__ __launch_bounds__(256) void scan3p(const int* __restrict__ partial,
                                              const int* __restrict__ pincl,
                                              const int* __restrict__ bsum, int nb,
                                              int* __restrict__ base,
                                              int* __restrict__ part_off, int E) {
    __shared__ int s[256];
    inline_bscan(bsum, nb, s);
    int i = blockIdx.x * blockDim.x + threadIdx.x;
    if (i < TOTP) {
        int v = pincl[i] + s[i >> 10] - partial[i];
        base[i] = v;
        if ((i & (NCHUNK - 1)) == 0) part_off[i / NCHUNK] = v;
    }
    if (i == 0) part_off[NBUCK] = E;
}

__global__ __launch_bounds__(256) void partition_edges(const int* __restrict__ src,
                                                       const int* __restrict__ dst,
                                                       const int* __restrict__ base,
                                                       unsigned* __restrict__ part,
                                                       int E, int chunk) {
    __shared__ int cur[NBUCK];
    int t = threadIdx.x, c = blockIdx.x;
    for (int b = t; b < NBUCK; b += 256) cur[b] = base[b * NCHUNK + c];
    __syncthreads();
    int lo = c * chunk, hi = min(lo + chunk, E);
    for (int i = lo + t; i < hi; i += 256) {
        int s = src[i], d = dst[i];
        int pos = atomicAdd(&cur[d >> 7], 1);
        part[pos] = (unsigned)s | ((unsigned)(d & (BROWS - 1)) << 17);
    }
}

__global__ __launch_bounds__(256) void deg_dis(const unsigned* __restrict__ part,
                                               const int* __restrict__ part_off,
                                               int* __restrict__ pdeg,
                                               float* __restrict__ dis, int n) {
    __shared__ int cnt[BROWS];
    int t = threadIdx.x, b = blockIdx.x;
    int r0 = b * BROWS;
    if (t < BROWS) cnt[t] = 0;
    __syncthreads();
    for (int i = part_off[b] + t; i < part_off[b + 1]; i += 256)
        atomicAdd(&cnt[part[i] >> 17], 1);
    __syncthreads();
    int nrows = min(BROWS, n - r0);
    if (t < nrows) {
        int dg = cnt[t];
        pdeg[r0 + t] = dg;                          // raw; scan1 applies pad8
        dis[r0 + t] = rsqrtf((float)(dg + 1));
    }
}

// stage/cne hold BYTE offsets (src * 128); pad slots -> N_NODES*128 (zero row).
__global__ __launch_bounds__(256) void build_csr(const unsigned* __restrict__ part,
                                                 const int* __restrict__ part_off,
                                                 const int* __restrict__ row_ptr,
                                                 unsigned* __restrict__ cne, int n) {
    __shared__ int fill[BROWS];
    __shared__ unsigned stage[CAP];
    int b = blockIdx.x;
    int r0 = b * BROWS;
    int t = threadIdx.x;
    int nrows = min(BROWS, n - r0);
    int base = row_ptr[r0];
    int region = row_ptr[r0 + nrows] - base;
    for (int r = t; r < nrows; r += 256) fill[r] = row_ptr[r0 + r] - base;
    int i0 = part_off[b], i1 = part_off[b + 1];
    if (region <= CAP) {
        for (int i = t; i < region; i += 256) stage[i] = (unsigned)N_NODES << 7;
        __syncthreads();
        for (int i = i0 + t; i < i1; i += 256) {
            unsigned pe = part[i];
            int pos = atomicAdd(&fill[pe >> 17], 1);
            stage[pos] = (pe & 0x1FFFFu) << 7;
        }
        __syncthreads();
        for (int i = t; i < region; i += 256) cne[base + i] = stage[i];
    } else {
        for (int i = t; i < region; i += 256) cne[base + i] = (unsigned)N_NODES << 7;
        __syncthreads();
        for (int i = i0 + t; i < i1; i += 256) {
            unsigned pe = part[i];
            int pos = atomicAdd(&fill[pe >> 17], 1);
            cne[base + pos] = (pe & 0x1FFFFu) << 7;
        }
    }
}

// ---------------- per-layer compute ----------------

// MFMA GEMM: out[row][col] = (half) dis[row] * sum_k X[row][k] * W[k][col]
// Used for layer 1 only (X = fp32 input x). Layouts verified (R11/R12 + guide m89/m91).
template <int K, typename XT>
__global__ __launch_bounds__(256) void gemm_mfma(const XT* __restrict__ X,
                                                 const float* __restrict__ W,
                                                 const float* __restrict__ dis,
                                                 __half* __restrict__ out, int n) {
    const int KS = K / 32;
    int wave = threadIdx.x >> 6, lane = threadIdx.x & 63;
    int quad = lane >> 4, l16 = lane & 15;
    h8 b[4][KS];
#pragma unroll
    for (int ct = 0; ct < 4; ct++)
#pragma unroll
        for (int ks = 0; ks < KS; ks++)
#pragma unroll
            for (int j = 0; j < 8; j++)
                b[ct][ks][j] = (_Float16)W[(ks * 32 + quad * 8 + j) * HID + ct * 16 + l16];
    int ntile = n >> 4;
    int wpb = blockDim.x >> 6;
    int stride = gridDim.x * wpb;
    for (int rt = blockIdx.x * wpb + wave; rt < ntile; rt += stride) {
        int row0 = rt << 4;
        const XT* xr = X + (size_t)(row0 + l16) * K + quad * 8;
        f4 acc[4];
#pragma unroll
        for (int ct = 0; ct < 4; ct++) acc[ct] = (f4)(0.f);
#pragma unroll
        for (int ks = 0; ks < KS; ks++) {
            h8 a;
            if constexpr (__is_same(XT, float)) {
                float4 xa = *(const float4*)(xr + ks * 32);
                float4 xb = *(const float4*)(xr + ks * 32 + 4);
                a[0] = (_Float16)xa.x; a[1] = (_Float16)xa.y;
                a[2] = (_Float16)xa.z; a[3] = (_Float16)xa.w;
                a[4] = (_Float16)xb.x; a[5] = (_Float16)xb.y;
                a[6] = (_Float16)xb.z; a[7] = (_Float16)xb.w;
            } else {
                a = *(const h8*)(xr + ks * 32);
            }
#pragma unroll
            for (int ct = 0; ct < 4; ct++)
                acc[ct] = __builtin_amdgcn_mfma_f32_16x16x32_f16(a, b[ct][ks], acc[ct], 0, 0, 0);
        }
        int r0 = row0 + quad * 4;
        float4 dv = *(const float4*)(dis + r0);
        float dd[4] = {dv.x, dv.y, dv.z, dv.w};
#pragma unroll
        for (int reg = 0; reg < 4; reg++) {
            __half* orow = out + (size_t)(r0 + reg) * HID + l16;
            orow[0]  = __float2half(dd[reg] * acc[0][reg]);
            orow[16] = __float2half(dd[reg] * acc[1][reg]);
            orow[32] = __float2half(dd[reg] * acc[2][reg]);
            orow[48] = __float2half(dd[reg] * acc[3][reg]);
        }
    }
}

// out[row] = relu( dis[row] * (tmp2[row] + sum_cols tmp2[col]) + bias ); pads read zero row N.
// half2 pairing: lane l -> column pair (2m,2m+1), m=l&31. Half hh takes edges 4*hh..4*hh+3
// of each 8-edge group: ONE int4 idx load per lane per group. cne holds byte offsets ->
// gather address is a single v_add onto the lane's base. Depth-2 pipeline.
template <typename OutT>
__global__ __launch_bounds__(256) void aggregate(const __half* __restrict__ tmp,
                                                 const float* __restrict__ dis,
                                                 const int* __restrict__ row_ptr,
                                                 const unsigned* __restrict__ cne,
                                                 const float* __restrict__ bias,
                                                 OutT* __restrict__ out, int n) {
    int wave = threadIdx.x >> 6, lane = threadIdx.x & 63;
    int m = lane & 31, hh = lane >> 5;
    const char* tbase = (const char*)tmp + 4 * m;   // lane's column-pair byte base
    int wpb = blockDim.x >> 6;
    int stride = gridDim.x * wpb;
    float2 blv = *(const float2*)(bias + 2 * m);
    for (int row = blockIdx.x * wpb + wave; row < n; row += stride) {
        float dr = dis[row];
        float ax0 = 0.f, ay0 = 0.f, ax1 = 0.f, ay1 = 0.f;
        float ax2 = 0.f, ay2 = 0.f, ax3 = 0.f, ay3 = 0.f;
        int s = row_ptr[row], e = row_ptr[row + 1];
        int ng = (e - s) >> 3;   // 8-edge groups (rows padded to 8)
        if (ng > 0) {
            const uint4* ip = (const uint4*)(cne + s) + hh;   // my half's int4 of group 0
            uint4 A = ip[0];
            __half2 g0 = *(const __half2*)(tbase + A.x);
            __half2 g1 = *(const __half2*)(tbase + A.y);
            __half2 g2 = *(const __half2*)(tbase + A.z);
            __half2 g3 = *(const __half2*)(tbase + A.w);
            uint4 B;
            if (ng > 1) B = ip[2];
            for (int g = 1; g < ng; g++) {
                __half2 u0 = *(const __half2*)(tbase + B.x);
                __half2 u1 = *(const __half2*)(tbase + B.y);
                __half2 u2 = *(const __half2*)(tbase + B.z);
                __half2 u3 = *(const __half2*)(tbase + B.w);
                if (g + 1 < ng) B = ip[2 * (g + 1)];
                float2 f0 = __half22float2(g0), f1 = __half22float2(g1);
                float2 f2 = __half22float2(g2), f3 = __half22float2(g3);
                ax0 += f0.x; ay0 += f0.y; ax1 += f1.x; ay1 += f1.y;
                ax2 += f2.x; ay2 += f2.y; ax3 += f3.x; ay3 += f3.y;
                g0 = u0; g1 = u1; g2 = u2; g3 = u3;
            }
            float2 f0 = __half22float2(g0), f1 = __half22float2(g1);
            float2 f2 = __half22float2(g2), f3 = __half22float2(g3);
            ax0 += f0.x; ay0 += f0.y; ax1 += f1.x; ay1 += f1.y;
            ax2 += f2.x; ay2 += f2.y; ax3 += f3.x; ay3 += f3.y;
        }
        float sx = (ax0 + ax1) + (ax2 + ax3);
        float sy = (ay0 + ay1) + (ay2 + ay3);
        sx += __shfl_xor(sx, 32);
        sy += __shfl_xor(sy, 32);
        float2 selff = __half22float2(*(const __half2*)(tbase + (size_t)row * 128));
        float rx = fmaxf(dr * (selff.x + sx) + blv.x, 0.f);
        float ry = fmaxf(dr * (selff.y + sy) + blv.y, 0.f);
        if (hh == 0) {
            if constexpr (__is_same(OutT, __half)) {
                *(__half2*)(out + row * HID + 2 * m) = __floats2half2_rn(rx, ry);
            } else {
                *(float2*)(out + row * HID + 2 * m) = make_float2(rx, ry);
            }
        }
    }
}

// Fused aggregate(layer k) + GEMM(layer k+1): block processes 16-row tiles.
// Each wave aggregates 4 rows (same inner loop as aggregate<>), h staged in LDS (fp16,
// identical rounding point as before), then each wave computes one 16-col MFMA slab of
// the next layer's dis-premultiplied tmp. Saves the h round trip through HBM/L3 + a launch.
__global__ __launch_bounds__(256) void fused_agg_gemm(const __half* __restrict__ tmp,
                                                      const float* __restrict__ dis,
                                                      const int* __restrict__ row_ptr,
                                                      const unsigned* __restrict__ cne,
                                                      const float* __restrict__ bias,
                                                      const float* __restrict__ W,
                                                      __half* __restrict__ out, int n) {
    __shared__ __half hs[16][72];   // +8 halves pad: 144B row stride -> 2-way-free banks
    int wave = threadIdx.x >> 6, lane = threadIdx.x & 63;
    int m = lane & 31, hh = lane >> 5;
    int quad = lane >> 4, l16 = lane & 15;
    const char* tbase = (const char*)tmp + 4 * m;
    float2 blv = *(const float2*)(bias + 2 * m);
    // hoist B-fragments for this wave's column slab (ct = wave)
    h8 b0, b1;
#pragma unroll
    for (int j = 0; j < 8; j++) {
        b0[j] = (_Float16)W[(quad * 8 + j) * HID + wave * 16 + l16];
        b1[j] = (_Float16)W[(32 + quad * 8 + j) * HID + wave * 16 + l16];
    }
    int ntile = n >> 4;
    for (int rt = blockIdx.x; rt < ntile; rt += gridDim.x) {
        int r0 = rt << 4;
        // ---- aggregate: 4 rows per wave ----
        for (int i = 0; i < 4; i++) {
            int row = r0 + (wave << 2) + i;
            float dr = dis[row];
            float ax0 = 0.f, ay0 = 0.f, ax1 = 0.f, ay1 = 0.f;
            float ax2 = 0.f, ay2 = 0.f, ax3 = 0.f, ay3 = 0.f;
            int s_ = row_ptr[row], e_ = row_ptr[row + 1];
            int ng = (e_ - s_) >> 3;
            if (ng > 0) {
                const uint4* ip = (const uint4*)(cne + s_) + hh;
                uint4 A = ip[0];
                __half2 g0 = *(const __half2*)(tbase + A.x);
                __half2 g1 = *(const __half2*)(tbase + A.y);
                __half2 g2 = *(const __half2*)(tbase + A.z);
                __half2 g3 = *(const __half2*)(tbase + A.w);
                uint4 B;
                if (ng > 1) B = ip[2];
                for (int g = 1; g < ng; g++) {
                    __half2 u0 = *(const __half2*)(tbase + B.x);
                    __half2 u1 = *(const __half2*)(tbase + B.y);
                    __half2 u2 = *(const __half2*)(tbase + B.z);
                    __half2 u3 = *(const __half2*)(tbase + B.w);
                    if (g + 1 < ng) B = ip[2 * (g + 1)];
                    float2 f0 = __half22float2(g0), f1 = __half22float2(g1);
                    float2 f2 = __half22float2(g2), f3 = __half22float2(g3);
                    ax0 += f0.x; ay0 += f0.y; ax1 += f1.x; ay1 += f1.y;
                    ax2 += f2.x; ay2 += f2.y; ax3 += f3.x; ay3 += f3.y;
                    g0 = u0; g1 = u1; g2 = u2; g3 = u3;
                }
                float2 f0 = __half22float2(g0), f1 = __half22float2(g1);
                float2 f2 = __half22float2(g2), f3 = __half22float2(g3);
                ax0 += f0.x; ay0 += f0.y; ax1 += f1.x; ay1 += f1.y;
                ax2 += f2.x; ay2 += f2.y; ax3 += f3.x; ay3 += f3.y;
            }
            float sx = (ax0 + ax1) + (ax2 + ax3);
            float sy = (ay0 + ay1) + (ay2 + ay3);
            sx += __shfl_xor(sx, 32);
            sy += __shfl_xor(sy, 32);
            float2 selff = __half22float2(*(const __half2*)(tbase + (size_t)row * 128));
            float rx = fmaxf(dr * (selff.x + sx) + blv.x, 0.f);
            float ry = fmaxf(dr * (selff.y + sy) + blv.y, 0.f);
            if (hh == 0) *(__half2*)&hs[(wave << 2) + i][2 * m] = __floats2half2_rn(rx, ry);
        }
        __syncthreads();
        // ---- gemm: 16x16x64 slab, ct = wave ----
        f4 acc = (f4)(0.f);
        h8 a0 = *(const h8*)&hs[l16][quad * 8];
        h8 a1 = *(const h8*)&hs[l16][32 + quad * 8];
        acc = __builtin_amdgcn_mfma_f32_16x16x32_f16(a0, b0, acc, 0, 0, 0);
        acc = __builtin_amdgcn_mfma_f32_16x16x32_f16(a1, b1, acc, 0, 0, 0);
        int rr = r0 + quad * 4;
        float4 dv = *(const float4*)(dis + rr);
        float dd[4] = {dv.x, dv.y, dv.z, dv.w};
#pragma unroll
        for (int reg = 0; reg < 4; reg++)
            out[(size_t)(rr + reg) * HID + wave * 16 + l16] = __float2half(dd[reg] * acc[reg]);
        __syncthreads();
    }
}

__global__ __launch_bounds__(256) void pool_kernel(const float* __restrict__ h,
                                                   const int* __restrict__ batch,
                                                   const float* __restrict__ Wout,
                                                   const float* __restrict__ bout,
                                                   float* __restrict__ d_out, int n) {
    __shared__ float ssum[4][64];
    __shared__ float smax[4][64];
    int g = blockIdx.x;
    int wave = threadIdx.x >> 6, j = threadIdx.x & 63;
    int lo = 0, hi = n;
    while (lo < hi) { int mid = (lo + hi) >> 1; if (batch[mid] < g) lo = mid + 1; else hi = mid; }
    int start = lo;
    hi = n;
    while (lo < hi) { int mid = (lo + hi) >> 1; if (batch[mid] < g + 1) lo = mid + 1; else hi = mid; }
    int end = lo;

    float sum = 0.f, mx = 0.f;
    for (int i = start + wave; i < end; i += 4) {
        float v = h[(size_t)i * HID + j];
        sum += v;
        mx = fmaxf(mx, v);
    }
    ssum[wave][j] = sum;
    smax[wave][j] = mx;
    __syncthreads();
    if (wave == 0) {
        sum = (ssum[0][j] + ssum[1][j]) + (ssum[2][j] + ssum[3][j]);
        mx = fmaxf(fmaxf(smax[0][j], smax[1][j]), fmaxf(smax[2][j], smax[3][j]));
        float cnt = (float)(end - start);
        float mean = sum / fmaxf(cnt, 1.f);
        float* pooled = d_out + NUM_GRAPHS;
        pooled[(size_t)g * (2 * HID) + j] = mean;
        pooled[(size_t)g * (2 * HID) + HID + j] = mx;
        float c = mean * Wout[j] + mx * Wout[HID + j];
#pragma unroll
        for (int off = 32; off; off >>= 1) c += __shfl_down(c, off);
        if (j == 0) d_out[g] = c + bout[0];
    }
}

// ---------------- launch ----------------

extern "C" void kernel_launch(void* const* d_in, const int* in_sizes, int n_in,
                              void* d_out, int out_size, void* d_ws, size_t ws_size,
                              hipStream_t stream) {
    const float* x    = (const float*)d_in[0];
    const int*   edge = (const int*)d_in[1];
    const int*   batch= (const int*)d_in[2];
    const float* W1 = (const float*)d_in[3];  const float* b1 = (const float*)d_in[4];
    const float* W2 = (const float*)d_in[5];  const float* b2 = (const float*)d_in[6];
    const float* W3 = (const float*)d_in[7];  const float* b3 = (const float*)d_in[8];
    const float* W4 = (const float*)d_in[9];  const float* b4 = (const float*)d_in[10];
    const float* Wout = (const float*)d_in[11]; const float* bout = (const float*)d_in[12];
    float* out = (float*)d_out;

    const int N = N_NODES;
    const int E = in_sizes[1] / 2;
    const int* src = edge;
    const int* dst = edge + E;
    const int chunk = (E + NCHUNK - 1) / NCHUNK;

    char* p = (char*)d_ws;
    auto alloc = [&](size_t bytes) -> char* {
        char* r = p;
        p += (bytes + 255) & ~(size_t)255;
        return r;
    };
    int*      pdeg     = (int*)alloc((size_t)N * 4);
    int*      row_ptr  = (int*)alloc((size_t)(N + 1) * 4);
    int*      partial  = (int*)alloc((size_t)TOTP * 4);
    int*      pincl    = (int*)alloc((size_t)TOTP * 4);
    int*      pbase    = (int*)alloc((size_t)TOTP * 4);
    int*      part_off = (int*)alloc((size_t)(NBUCK + 1) * 4);
    unsigned* part     = (unsigned*)alloc((size_t)1600000 * 4);
    unsigned* cne      = (unsigned*)alloc((size_t)CNE_MAX * 4);
    float*    dis      = (float*)alloc((size_t)N * 4);
    int*      bsum     = (int*)alloc(256 * 4);
    __half*   tmpA     = (__half*)alloc((size_t)(N + 1) * HID * 2);
    __half*   tmpB     = (__half*)alloc((size_t)(N + 1) * HID * 2);
    float*    hA       = (float*)alloc((size_t)N * HID * 4);

    hist_partial<<<NCHUNK, 256, 0, stream>>>(dst, partial, E, chunk,
                                             (unsigned*)(tmpA + (size_t)N * HID),
                                             (unsigned*)(tmpB + (size_t)N * HID));
    int nbp = (TOTP + 1023) / 1024;   // 196
    scan1<<<nbp, 256, 0, stream>>>(partial, pincl, bsum, TOTP, 0);
    scan3p<<<(TOTP + 255) / 256, 256, 0, stream>>>(partial, pincl, bsum, nbp, pbase, part_off, E);
    partition_edges<<<NCHUNK, 256, 0, stream>>>(src, dst, pbase, part, E, chunk);
    deg_dis<<<NBUCK, 256, 0, stream>>>(part, part_off, pdeg, dis, N);

    int nb = (N + 1023) / 1024;   // 98
    scan1<<<nb, 256, 0, stream>>>(pdeg, row_ptr + 1, bsum, N, 1);
    scan3<<<(N + 255) / 256, 256, 0, stream>>>(row_ptr, bsum, nb, N);
    build_csr<<<NBUCK, 256, 0, stream>>>(part, part_off, row_ptr, cne, N);

    const int AGG_BLOCKS = 2048;
    const int GEMM_BLOCKS = 1024;

    gemm_mfma<IN_DIM, float><<<GEMM_BLOCKS, 256, 0, stream>>>(x, W1, dis, tmpA, N);
    fused_agg_gemm<<<AGG_BLOCKS, 256, 0, stream>>>(tmpA, dis, row_ptr, cne, b1, W2, tmpB, N);
    fused_agg_gemm<<<AGG_BLOCKS, 256, 0, stream>>>(tmpB, dis, row_ptr, cne, b2, W3, tmpA, N);
    fused_agg_gemm<<<AGG_BLOCKS, 256, 0, stream>>>(tmpA, dis, row_ptr, cne, b3, W4, tmpB, N);
    aggregate<float><<<AGG_BLOCKS, 256, 0, stream>>>(tmpB, dis, row_ptr, cne, b4, hA, N);

    pool_kernel<<<NUM_GRAPHS, 256, 0, stream>>>(hA, batch, Wout, bout, out, N);
}

// Round 2
// 343.196 us; speedup vs baseline: 1.1092x; 1.1092x over previous
//
#include <hip/hip_runtime.h>
#include <hip/hip_fp16.h>

#define N_NODES 100000
#define IN_DIM 128
#define HID 64
#define NUM_GRAPHS 2048
#define CNE_MAX (1600000 + 7 * N_NODES)   // padded-to-8 CSR upper bound
#define BROWS 128                          // rows per bucket
#define NBUCK ((N_NODES + BROWS - 1) / BROWS)   // 782
#define NCHUNK 256                         // edge chunks (one block each)
#define TOTP (NBUCK * NCHUNK)              // 200192 partial counters
#define CAP 4096                           // LDS staging entries per bucket

typedef _Float16 h8 __attribute__((ext_vector_type(8)));
typedef float f4 __attribute__((ext_vector_type(4)));

// ---------------- build phase (NO per-edge global atomics anywhere) ----------------

// also zeroes the pad row (row N) of tmp (replaces a memset dispatch)
__global__ __launch_bounds__(256) void hist_partial(const int* __restrict__ dst,
                                                    int* __restrict__ partial,
                                                    int E, int chunk,
                                                    unsigned* __restrict__ padA,
                                                    unsigned* __restrict__ padB) {
    __shared__ int lh[NBUCK];
    int t = threadIdx.x, c = blockIdx.x;
    if (c == 0) {
        if (t < 32) padA[t] = 0;
        else if (t < 64) padB[t - 32] = 0;
    }
    for (int b = t; b < NBUCK; b += 256) lh[b] = 0;
    __syncthreads();
    int lo = c * chunk, hi = min(lo + chunk, E);
    for (int i = lo + t; i < hi; i += 256) atomicAdd(&lh[dst[i] >> 7], 1);
    __syncthreads();
    for (int b = t; b < NBUCK; b += 256) partial[b * NCHUNK + c] = lh[b];
}

// phase 1: per-block (1024 elems) inclusive scan + block sums; pad8 applied when flagged
__global__ void scan1(const int* __restrict__ counts, int* __restrict__ out1,
                      int* __restrict__ bsum, int n, int pad8) {
    __shared__ int s[256];
    int t = threadIdx.x;
    int base = blockIdx.x * 1024 + t * 4;
    int v[4];
#pragma unroll
    for (int i = 0; i < 4; i++) {
        int c = (base + i < n) ? counts[base + i] : 0;
        v[i] = pad8 ? ((c + 7) & ~7) : c;
    }
    int tsum = v[0] + v[1] + v[2] + v[3];
    s[t] = tsum;
    __syncthreads();
    for (int off = 1; off < 256; off <<= 1) {
        int tv = (t >= off) ? s[t - off] : 0;
        __syncthreads();
        s[t] += tv;
        __syncthreads();
    }
    int excl = s[t] - tsum;
    if (t == 255) bsum[blockIdx.x] = s[255];
    int run = excl;
#pragma unroll
    for (int i = 0; i < 4; i++) {
        run += v[i];
        if (base + i < n) out1[base + i] = run;
    }
}

// scan of block sums (nb <= 256) done redundantly per block in LDS (removes scan2 dispatch)
__device__ __forceinline__ int inline_bscan(const int* __restrict__ bsum, int nb, int* s) {
    int t = threadIdx.x;
    int v = (t < nb) ? bsum[t] : 0;
    s[t] = v;
    __syncthreads();
    for (int off = 1; off < 256; off <<= 1) {
        int tv = (t >= off) ? s[t - off] : 0;
        __syncthreads();
        s[t] += tv;
        __syncthreads();
    }
    int excl = s[t] - v;
    __syncthreads();
    s[t] = excl;
    __syncthreads();
    return excl;
}

__global__ __launch_bounds__(256) void scan3(int* __restrict__ row_ptr,
                                             const int* __restrict__ bsum, int nb, int n) {
    __shared__ int s[256];
    inline_bscan(bsum, nb, s);
    int i = blockIdx.x * blockDim.x + threadIdx.x;
    if (i == 0) row_ptr[0] = 0;
    if (i < n) row_ptr[i + 1] += s[i >> 10];
}

__global__ __launch_bounds__(256) void scan3p(const int* __restrict__ partial,
                                              const int* __restrict__ pincl,
                                              const int* __restrict__ bsum, int nb,
                                              int* __restrict__ base,
                                              int* __restrict__ part_off, int E) {
    __shared__ int s[256];
    inline_bscan(bsum, nb, s);
    int i = blockIdx.x * blockDim.x + threadIdx.x;
    if (i < TOTP) {
        int v = pincl[i] + s[i >> 10] - partial[i];
        base[i] = v;
        if ((i & (NCHUNK - 1)) == 0) part_off[i / NCHUNK] = v;
    }
    if (i == 0) part_off[NBUCK] = E;
}

__global__ __launch_bounds__(256) void partition_edges(const int* __restrict__ src,
                                                       const int* __restrict__ dst,
                                                       const int* __restrict__ base,
                                                       unsigned* __restrict__ part,
                                                       int E, int chunk) {
    __shared__ int cur[NBUCK];
    int t = threadIdx.x, c = blockIdx.x;
    for (int b = t; b < NBUCK; b += 256) cur[b] = base[b * NCHUNK + c];
    __syncthreads();
    int lo = c * chunk, hi = min(lo + chunk, E);
    for (int i = lo + t; i < hi; i += 256) {
        int s = src[i], d = dst[i];
        int pos = atomicAdd(&cur[d >> 7], 1);
        part[pos] = (unsigned)s | ((unsigned)(d & (BROWS - 1)) << 17);
    }
}

__global__ __launch_bounds__(256) void deg_dis(const unsigned* __restrict__ part,
                                               const int* __restrict__ part_off,
                                               int* __restrict__ pdeg,
                                               float* __restrict__ dis, int n) {
    __shared__ int cnt[BROWS];
    int t = threadIdx.x, b = blockIdx.x;
    int r0 = b * BROWS;
    if (t < BROWS) cnt[t] = 0;
    __syncthreads();
    for (int i = part_off[b] + t; i < part_off[b + 1]; i += 256)
        atomicAdd(&cnt[part[i] >> 17], 1);
    __syncthreads();
    int nrows = min(BROWS, n - r0);
    if (t < nrows) {
        int dg = cnt[t];
        pdeg[r0 + t] = dg;                          // raw; scan1 applies pad8
        dis[r0 + t] = rsqrtf((float)(dg + 1));
    }
}

// stage/cne hold BYTE offsets (src * 128); pad slots -> N_NODES*128 (zero row).
__global__ __launch_bounds__(256) void build_csr(const unsigned* __restrict__ part,
                                                 const int* __restrict__ part_off,
                                                 const int* __restrict__ row_ptr,
                                                 unsigned* __restrict__ cne, int n) {
    __shared__ int fill[BROWS];
    __shared__ unsigned stage[CAP];
    int b = blockIdx.x;
    int r0 = b * BROWS;
    int t = threadIdx.x;
    int nrows = min(BROWS, n - r0);
    int base = row_ptr[r0];
    int region = row_ptr[r0 + nrows] - base;
    for (int r = t; r < nrows; r += 256) fill[r] = row_ptr[r0 + r] - base;
    int i0 = part_off[b], i1 = part_off[b + 1];
    if (region <= CAP) {
        for (int i = t; i < region; i += 256) stage[i] = (unsigned)N_NODES << 7;
        __syncthreads();
        for (int i = i0 + t; i < i1; i += 256) {
            unsigned pe = part[i];
            int pos = atomicAdd(&fill[pe >> 17], 1);
            stage[pos] = (pe & 0x1FFFFu) << 7;
        }
        __syncthreads();
        for (int i = t; i < region; i += 256) cne[base + i] = stage[i];
    } else {
        for (int i = t; i < region; i += 256) cne[base + i] = (unsigned)N_NODES << 7;
        __syncthreads();
        for (int i = i0 + t; i < i1; i += 256) {
            unsigned pe = part[i];
            int pos = atomicAdd(&fill[pe >> 17], 1);
            cne[base + pos] = (pe & 0x1FFFFu) << 7;
        }
    }
}

// ---------------- per-layer compute ----------------

// MFMA GEMM: out[row][col] = (half) dis[row] * sum_k X[row][k] * W[k][col]
// XT = float (layer 1) or _Float16 (h from previous layer; A-frag = direct 16 B load).
// B-fragments built in-register from fp32 W. Layouts verified (R11/R12 + guide m89/m91).
template <int K, typename XT>
__global__ __launch_bounds__(256) void gemm_mfma(const XT* __restrict__ X,
                                                 const float* __restrict__ W,
                                                 const float* __restrict__ dis,
                                                 __half* __restrict__ out, int n) {
    const int KS = K / 32;
    int wave = threadIdx.x >> 6, lane = threadIdx.x & 63;
    int quad = lane >> 4, l16 = lane & 15;
    h8 b[4][KS];
#pragma unroll
    for (int ct = 0; ct < 4; ct++)
#pragma unroll
        for (int ks = 0; ks < KS; ks++)
#pragma unroll
            for (int j = 0; j < 8; j++)
                b[ct][ks][j] = (_Float16)W[(ks * 32 + quad * 8 + j) * HID + ct * 16 + l16];
    int ntile = n >> 4;
    int wpb = blockDim.x >> 6;
    int stride = gridDim.x * wpb;
    for (int rt = blockIdx.x * wpb + wave; rt < ntile; rt += stride) {
        int row0 = rt << 4;
        const XT* xr = X + (size_t)(row0 + l16) * K + quad * 8;
        f4 acc[4];
#pragma unroll
        for (int ct = 0; ct < 4; ct++) acc[ct] = (f4)(0.f);
#pragma unroll
        for (int ks = 0; ks < KS; ks++) {
            h8 a;
            if constexpr (__is_same(XT, float)) {
                float4 xa = *(const float4*)(xr + ks * 32);
                float4 xb = *(const float4*)(xr + ks * 32 + 4);
                a[0] = (_Float16)xa.x; a[1] = (_Float16)xa.y;
                a[2] = (_Float16)xa.z; a[3] = (_Float16)xa.w;
                a[4] = (_Float16)xb.x; a[5] = (_Float16)xb.y;
                a[6] = (_Float16)xb.z; a[7] = (_Float16)xb.w;
            } else {
                a = *(const h8*)(xr + ks * 32);
            }
#pragma unroll
            for (int ct = 0; ct < 4; ct++)
                acc[ct] = __builtin_amdgcn_mfma_f32_16x16x32_f16(a, b[ct][ks], acc[ct], 0, 0, 0);
        }
        int r0 = row0 + quad * 4;
        float4 dv = *(const float4*)(dis + r0);
        float dd[4] = {dv.x, dv.y, dv.z, dv.w};
#pragma unroll
        for (int reg = 0; reg < 4; reg++) {
            __half* orow = out + (size_t)(r0 + reg) * HID + l16;
            orow[0]  = __float2half(dd[reg] * acc[0][reg]);
            orow[16] = __float2half(dd[reg] * acc[1][reg]);
            orow[32] = __float2half(dd[reg] * acc[2][reg]);
            orow[48] = __float2half(dd[reg] * acc[3][reg]);
        }
    }
}

// out[row] = relu( dis[row] * (tmp[row] + sum_cols tmp[col]) + bias ); pads read zero row N.
// Dual-row lane layout: 64 lanes = 32 column-pairs (m = lane&31) x 2 ROWS (hh = lane>>5).
// Lane owns row 2p+hh and processes ALL 8 edges of each group itself: 2 uint4 idx loads
// + 8 half2 gathers in flight per lane (16 with depth-2 prefetch) -> 2x the memory-level
// parallelism of the edge-split layout, no cross-lane reduce, no barriers. Divergence when
// paired rows have different group counts costs E[max]/E[ng] ~ 1.13x, << the 2x MLP gain.
template <typename OutT>
__global__ __launch_bounds__(256) void aggregate2(const __half* __restrict__ tmp,
                                                  const float* __restrict__ dis,
                                                  const int* __restrict__ row_ptr,
                                                  const unsigned* __restrict__ cne,
                                                  const float* __restrict__ bias,
                                                  OutT* __restrict__ out, int n) {
    int wave = threadIdx.x >> 6, lane = threadIdx.x & 63;
    int m = lane & 31, hh = lane >> 5;
    const char* tbase = (const char*)tmp + 4 * m;   // lane's column-pair byte base
    int wpb = blockDim.x >> 6;
    int stride = gridDim.x * wpb;
    float2 blv = *(const float2*)(bias + 2 * m);
    int npairs = n >> 1;
    for (int p = blockIdx.x * wpb + wave; p < npairs; p += stride) {
        int row = 2 * p + hh;
        float dr = dis[row];
        int s = row_ptr[row], e = row_ptr[row + 1];
        int ng = (e - s) >> 3;   // 8-edge groups (rows padded to 8)
        float ax0 = 0.f, ay0 = 0.f, ax1 = 0.f, ay1 = 0.f;
        float ax2 = 0.f, ay2 = 0.f, ax3 = 0.f, ay3 = 0.f;
        if (ng > 0) {
            const uint4* ip = (const uint4*)(cne + s);
            uint4 A0 = ip[0], A1 = ip[1];
            __half2 g0 = *(const __half2*)(tbase + A0.x);
            __half2 g1 = *(const __half2*)(tbase + A0.y);
            __half2 g2 = *(const __half2*)(tbase + A0.z);
            __half2 g3 = *(const __half2*)(tbase + A0.w);
            __half2 g4 = *(const __half2*)(tbase + A1.x);
            __half2 g5 = *(const __half2*)(tbase + A1.y);
            __half2 g6 = *(const __half2*)(tbase + A1.z);
            __half2 g7 = *(const __half2*)(tbase + A1.w);
            uint4 B0, B1;
            if (ng > 1) { B0 = ip[2]; B1 = ip[3]; }
            for (int g = 1; g < ng; g++) {
                __half2 u0 = *(const __half2*)(tbase + B0.x);
                __half2 u1 = *(const __half2*)(tbase + B0.y);
                __half2 u2 = *(const __half2*)(tbase + B0.z);
                __half2 u3 = *(const __half2*)(tbase + B0.w);
                __half2 u4 = *(const __half2*)(tbase + B1.x);
                __half2 u5 = *(const __half2*)(tbase + B1.y);
                __half2 u6 = *(const __half2*)(tbase + B1.z);
                __half2 u7 = *(const __half2*)(tbase + B1.w);
                if (g + 1 < ng) { B0 = ip[2 * (g + 1)]; B1 = ip[2 * (g + 1) + 1]; }
                float2 f0 = __half22float2(g0), f1 = __half22float2(g1);
                float2 f2 = __half22float2(g2), f3 = __half22float2(g3);
                float2 f4 = __half22float2(g4), f5 = __half22float2(g5);
                float2 f6 = __half22float2(g6), f7 = __half22float2(g7);
                ax0 += f0.x; ay0 += f0.y; ax1 += f1.x; ay1 += f1.y;
                ax2 += f2.x; ay2 += f2.y; ax3 += f3.x; ay3 += f3.y;
                ax0 += f4.x; ay0 += f4.y; ax1 += f5.x; ay1 += f5.y;
                ax2 += f6.x; ay2 += f6.y; ax3 += f7.x; ay3 += f7.y;
                g0 = u0; g1 = u1; g2 = u2; g3 = u3;
                g4 = u4; g5 = u5; g6 = u6; g7 = u7;
            }
            float2 f0 = __half22float2(g0), f1 = __half22float2(g1);
            float2 f2 = __half22float2(g2), f3 = __half22float2(g3);
            float2 f4 = __half22float2(g4), f5 = __half22float2(g5);
            float2 f6 = __half22float2(g6), f7 = __half22float2(g7);
            ax0 += f0.x; ay0 += f0.y; ax1 += f1.x; ay1 += f1.y;
            ax2 += f2.x; ay2 += f2.y; ax3 += f3.x; ay3 += f3.y;
            ax0 += f4.x; ay0 += f4.y; ax1 += f5.x; ay1 += f5.y;
            ax2 += f6.x; ay2 += f6.y; ax3 += f7.x; ay3 += f7.y;
        }
        float sx = (ax0 + ax1) + (ax2 + ax3);
        float sy = (ay0 + ay1) + (ay2 + ay3);
        float2 selff = __half22float2(*(const __half2*)(tbase + (size_t)row * 128));
        float rx = fmaxf(dr * (selff.x + sx) + blv.x, 0.f);
        float ry = fmaxf(dr * (selff.y + sy) + blv.y, 0.f);
        if constexpr (__is_same(OutT, __half)) {
            *(__half2*)(out + (size_t)row * HID + 2 * m) = __floats2half2_rn(rx, ry);
        } else {
            *(float2*)(out + (size_t)row * HID + 2 * m) = make_float2(rx, ry);
        }
    }
}

__global__ __launch_bounds__(256) void pool_kernel(const float* __restrict__ h,
                                                   const int* __restrict__ batch,
                                                   const float* __restrict__ Wout,
                                                   const float* __restrict__ bout,
                                                   float* __restrict__ d_out, int n) {
    __shared__ float ssum[4][64];
    __shared__ float smax[4][64];
    int g = blockIdx.x;
    int wave = threadIdx.x >> 6, j = threadIdx.x & 63;
    int lo = 0, hi = n;
    while (lo < hi) { int mid = (lo + hi) >> 1; if (batch[mid] < g) lo = mid + 1; else hi = mid; }
    int start = lo;
    hi = n;
    while (lo < hi) { int mid = (lo + hi) >> 1; if (batch[mid] < g + 1) lo = mid + 1; else hi = mid; }
    int end = lo;

    float sum = 0.f, mx = 0.f;
    for (int i = start + wave; i < end; i += 4) {
        float v = h[(size_t)i * HID + j];
        sum += v;
        mx = fmaxf(mx, v);
    }
    ssum[wave][j] = sum;
    smax[wave][j] = mx;
    __syncthreads();
    if (wave == 0) {
        sum = (ssum[0][j] + ssum[1][j]) + (ssum[2][j] + ssum[3][j]);
        mx = fmaxf(fmaxf(smax[0][j], smax[1][j]), fmaxf(smax[2][j], smax[3][j]));
        float cnt = (float)(end - start);
        float mean = sum / fmaxf(cnt, 1.f);
        float* pooled = d_out + NUM_GRAPHS;
        pooled[(size_t)g * (2 * HID) + j] = mean;
        pooled[(size_t)g * (2 * HID) + HID + j] = mx;
        float c = mean * Wout[j] + mx * Wout[HID + j];
#pragma unroll
        for (int off = 32; off; off >>= 1) c += __shfl_down(c, off);
        if (j == 0) d_out[g] = c + bout[0];
    }
}

// ---------------- launch ----------------

extern "C" void kernel_launch(void* const* d_in, const int* in_sizes, int n_in,
                              void* d_out, int out_size, void* d_ws, size_t ws_size,
                              hipStream_t stream) {
    const float* x    = (const float*)d_in[0];
    const int*   edge = (const int*)d_in[1];
    const int*   batch= (const int*)d_in[2];
    const float* W1 = (const float*)d_in[3];  const float* b1 = (const float*)d_in[4];
    const float* W2 = (const float*)d_in[5];  const float* b2 = (const float*)d_in[6];
    const float* W3 = (const float*)d_in[7];  const float* b3 = (const float*)d_in[8];
    const float* W4 = (const float*)d_in[9];  const float* b4 = (const float*)d_in[10];
    const float* Wout = (const float*)d_in[11]; const float* bout = (const float*)d_in[12];
    float* out = (float*)d_out;

    const int N = N_NODES;
    const int E = in_sizes[1] / 2;
    const int* src = edge;
    const int* dst = edge + E;
    const int chunk = (E + NCHUNK - 1) / NCHUNK;

    char* p = (char*)d_ws;
    auto alloc = [&](size_t bytes) -> char* {
        char* r = p;
        p += (bytes + 255) & ~(size_t)255;
        return r;
    };
    int*      pdeg     = (int*)alloc((size_t)N * 4);
    int*      row_ptr  = (int*)alloc((size_t)(N + 1) * 4);
    int*      partial  = (int*)alloc((size_t)TOTP * 4);
    int*      pincl    = (int*)alloc((size_t)TOTP * 4);
    int*      pbase    = (int*)alloc((size_t)TOTP * 4);
    int*      part_off = (int*)alloc((size_t)(NBUCK + 1) * 4);
    unsigned* part     = (unsigned*)alloc((size_t)1600000 * 4);
    unsigned* cne      = (unsigned*)alloc((size_t)CNE_MAX * 4);
    float*    dis      = (float*)alloc((size_t)N * 4);
    int*      bsum     = (int*)alloc(256 * 4);
    __half*   tmp      = (__half*)alloc((size_t)(N + 1) * HID * 2);
    float*    hA       = (float*)alloc((size_t)N * HID * 4);
    __half*   hH       = (__half*)hA;   // fp16 h aliases front of hA (hA dead until agg4)

    unsigned* padrow = (unsigned*)(tmp + (size_t)N * HID);
    hist_partial<<<NCHUNK, 256, 0, stream>>>(dst, partial, E, chunk, padrow, padrow);
    int nbp = (TOTP + 1023) / 1024;   // 196
    scan1<<<nbp, 256, 0, stream>>>(partial, pincl, bsum, TOTP, 0);
    scan3p<<<(TOTP + 255) / 256, 256, 0, stream>>>(partial, pincl, bsum, nbp, pbase, part_off, E);
    partition_edges<<<NCHUNK, 256, 0, stream>>>(src, dst, pbase, part, E, chunk);
    deg_dis<<<NBUCK, 256, 0, stream>>>(part, part_off, pdeg, dis, N);

    int nb = (N + 1023) / 1024;   // 98
    scan1<<<nb, 256, 0, stream>>>(pdeg, row_ptr + 1, bsum, N, 1);
    scan3<<<(N + 255) / 256, 256, 0, stream>>>(row_ptr, bsum, nb, N);
    build_csr<<<NBUCK, 256, 0, stream>>>(part, part_off, row_ptr, cne, N);

    const int AGG_BLOCKS = 2048;
    const int GEMM_BLOCKS = 1024;

    gemm_mfma<IN_DIM, float><<<GEMM_BLOCKS, 256, 0, stream>>>(x, W1, dis, tmp, N);
    aggregate2<__half><<<AGG_BLOCKS, 256, 0, stream>>>(tmp, dis, row_ptr, cne, b1, hH, N);
    gemm_mfma<HID, _Float16><<<GEMM_BLOCKS, 256, 0, stream>>>((_Float16*)hH, W2, dis, tmp, N);
    aggregate2<__half><<<AGG_BLOCKS, 256, 0, stream>>>(tmp, dis, row_ptr, cne, b2, hH, N);
    gemm_mfma<HID, _Float16><<<GEMM_BLOCKS, 256, 0, stream>>>((_Float16*)hH, W3, dis, tmp, N);
    aggregate2<__half><<<AGG_BLOCKS, 256, 0, stream>>>(tmp, dis, row_ptr, cne, b3, hH, N);
    gemm_mfma<HID, _Float16><<<GEMM_BLOCKS, 256, 0, stream>>>((_Float16*)hH, W4, dis, tmp, N);
    aggregate2<float><<<AGG_BLOCKS, 256, 0, stream>>>(tmp, dis, row_ptr, cne, b4, hA, N);

    pool_kernel<<<NUM_GRAPHS, 256, 0, stream>>>(hA, batch, Wout, bout, out, N);
}